// Round 5
// baseline (636.777 us; speedup 1.0000x reference)
//
#include <hip/hip_runtime.h>

#define NNODES 100000
#define NEDGES 1600000
#define NBKT 782          // buckets of 128 nodes: 782*128 = 100096 >= NNODES

typedef __attribute__((ext_vector_type(8))) short bf16x8;
typedef __attribute__((ext_vector_type(4))) float f32x4;
typedef __attribute__((ext_vector_type(2))) float f32x2;

// ---------- bf16 helpers ----------
__device__ __forceinline__ float bf2f(unsigned v) {
  union { unsigned u; float f; } x; x.u = v << 16; return x.f;
}
__device__ __forceinline__ unsigned short f2bf(float f) {
  union { float f; unsigned u; } x; x.f = f;
  unsigned r = x.u + 0x7fffu + ((x.u >> 16) & 1u);
  return (unsigned short)(r >> 16);
}
// unpack u32 (2 bf16) -> f32 pair for v_pk_fma_f32
__device__ __forceinline__ f32x2 unpk(unsigned u) {
  union { unsigned q; float f; } lo, hi;
  lo.q = u << 16; hi.q = u & 0xffff0000u;
  f32x2 r; r.x = lo.f; r.y = hi.f; return r;
}

// ---------- dtype probing (+ zero bcnt) ----------
__global__ void k_probe(const unsigned* __restrict__ xw, const int* __restrict__ ei,
                        int* __restrict__ flags, int* __restrict__ bcnt) {
  __shared__ int cF, cI;
  if (threadIdx.x == 0) { cF = 0; cI = 0; }
  __syncthreads();
  int t = threadIdx.x;
  int hf = 0;
  for (int i = t; i < 2048; i += 256) {
    unsigned lo = xw[i] & 0xffffu;
    unsigned e = (lo >> 7) & 0xffu;
    if (e >= 0xC0u) hf++;
  }
  atomicAdd(&cF, hf);
  int hi = 0;
  if (ei[2 * t + 1] != 0) hi++;
  atomicAdd(&cI, hi);
  for (int i = t; i < NBKT; i += 256) bcnt[i] = 0;
  __syncthreads();
  if (threadIdx.x == 0) {
    flags[0] = (cF > 32) ? 1 : 0;
    flags[1] = (cI < 16) ? 1 : 0;
  }
}

__device__ __forceinline__ int edge_at(const int* __restrict__ ei, int j, int i64) {
  return i64 ? ei[2 * j] : ei[j];
}

// ---------- canonicalize float arrays to bf16 ----------
// a==0 (x) additionally writes xs = x * dinv[row] (prescaled for aggregation)
struct CvtParams {
  const void* src[13];
  unsigned short* dst[13];
  int n[13];
};

__global__ void k_cvt(CvtParams p, const int* __restrict__ flags,
                      const float* __restrict__ dinv, unsigned short* __restrict__ xs) {
  int a = blockIdx.y;
  int n = p.n[a];
  int f32 = flags[0];
  const float* sf = (const float*)p.src[a];
  const unsigned short* sb = (const unsigned short*)p.src[a];
  unsigned short* d = p.dst[a];
  for (int i = blockIdx.x * blockDim.x + threadIdx.x; i < n; i += gridDim.x * blockDim.x) {
    if (a == 0) {
      float v = f32 ? sf[i] : bf2f((unsigned)sb[i]);
      d[i] = f32 ? f2bf(v) : sb[i];
      xs[i] = f2bf(v * dinv[i >> 7]);
    } else {
      d[i] = f32 ? f2bf(sf[i]) : sb[i];
    }
  }
}

// ---------- fused weight prep (all transposes in one launch) ----------
// jobs: 0: Wc0[128,256]->WTc0[256,128]; 1: Wc1[256,256]->WTc1[256,256];
//       2..5: We*[K,40]->WT40[48,K] (rows 40..47 zero)
__global__ void k_wprep(const unsigned short* __restrict__ Wc0, unsigned short* __restrict__ WTc0,
                        const unsigned short* __restrict__ Wc1, unsigned short* __restrict__ WTc1,
                        const unsigned short* __restrict__ We0, unsigned short* __restrict__ WT40e0,
                        const unsigned short* __restrict__ We1, unsigned short* __restrict__ WT40e1,
                        const unsigned short* __restrict__ We2, unsigned short* __restrict__ WT40e2,
                        const unsigned short* __restrict__ We3, unsigned short* __restrict__ WT40e3) {
  int job = blockIdx.y;
  int idx = blockIdx.x * 256 + threadIdx.x;
  switch (job) {
    case 0: if (idx < 128 * 256) { int k = idx >> 8, c = idx & 255; WTc0[c * 128 + k] = Wc0[idx]; } break;
    case 1: if (idx < 256 * 256) { int k = idx >> 8, c = idx & 255; WTc1[c * 256 + k] = Wc1[idx]; } break;
    case 2: if (idx < 48 * 128) { int c = idx / 128, k = idx % 128; WT40e0[idx] = (c < 40) ? We0[k * 40 + c] : (unsigned short)0; } break;
    case 3: if (idx < 48 * 128) { int c = idx / 128, k = idx % 128; WT40e1[idx] = (c < 40) ? We1[k * 40 + c] : (unsigned short)0; } break;
    case 4: if (idx < 48 * 256) { int c = idx / 256, k = idx % 256; WT40e2[idx] = (c < 40) ? We2[k * 40 + c] : (unsigned short)0; } break;
    case 5: if (idx < 48 * 256) { int c = idx / 256, k = idx % 256; WT40e3[idx] = (c < 40) ? We3[k * 40 + c] : (unsigned short)0; } break;
  }
}

// ---------- bucketed CSR build (no global per-edge atomics) ----------
// Bucket b = dst >> 7 covers nodes [128b, 128b+128). Record: (dstloc<<17)|src.

// pass 1: per-block LDS histogram over buckets -> aggregated global adds
__global__ __launch_bounds__(256) void k_bcnt(const int* __restrict__ ei,
                                              int* __restrict__ bcnt,
                                              const int* __restrict__ flags) {
  __shared__ int h[NBKT];
  int t = threadIdx.x;
  for (int i = t; i < NBKT; i += 256) h[i] = 0;
  __syncthreads();
  int i64 = flags[1];
  int e0 = blockIdx.x * 4096;
#pragma unroll
  for (int k = 0; k < 16; ++k) {
    int e = e0 + t + k * 256;
    if (e < NEDGES) {
      int d = edge_at(ei, NEDGES + e, i64);
      if ((unsigned)d < NNODES) atomicAdd(&h[d >> 7], 1);
    }
  }
  __syncthreads();
  for (int i = t; i < NBKT; i += 256)
    if (h[i]) atomicAdd(&bcnt[i], h[i]);
}

// scan 782 bucket counts -> bbase[0..782], init gcur
__global__ void k_bscan2(const int* __restrict__ bcnt, int* __restrict__ bbase,
                         int* __restrict__ gcur) {
  int l = threadIdx.x;  // 64 lanes
  int v[13];
  int s = 0;
#pragma unroll
  for (int k = 0; k < 13; ++k) {
    int j = l * 13 + k;
    v[k] = (j < NBKT) ? bcnt[j] : 0;
    s += v[k];
  }
  int x = s;
#pragma unroll
  for (int o = 1; o < 64; o <<= 1) {
    int y = __shfl_up(x, o, 64);
    if (l >= o) x += y;
  }
  int excl = x - s;
#pragma unroll
  for (int k = 0; k < 13; ++k) {
    int j = l * 13 + k;
    if (j < NBKT) { bbase[j] = excl; gcur[j] = excl; }
    excl += v[k];
  }
  if (l == 63) bbase[NBKT] = x;
}

// pass 2: stage records bucket-contiguously (block-aggregated reservations)
__global__ __launch_bounds__(256) void k_bstage(const int* __restrict__ ei,
                                                int* __restrict__ gcur,
                                                int* __restrict__ stage,
                                                const int* __restrict__ flags) {
  __shared__ int h[NBKT];
  __shared__ int base[NBKT];
  int t = threadIdx.x;
  for (int i = t; i < NBKT; i += 256) h[i] = 0;
  __syncthreads();
  int i64 = flags[1];
  int e0 = blockIdx.x * 4096;
  int bkt[16], lp[16], rec[16];
#pragma unroll
  for (int k = 0; k < 16; ++k) {
    bkt[k] = -1;
    int e = e0 + t + k * 256;
    if (e < NEDGES) {
      int d = edge_at(ei, NEDGES + e, i64);
      if ((unsigned)d < NNODES) {
        int s = edge_at(ei, e, i64);
        if ((unsigned)s >= NNODES) s = NNODES - 1;
        bkt[k] = d >> 7;
        rec[k] = ((d & 127) << 17) | s;
        lp[k] = atomicAdd(&h[bkt[k]], 1);
      }
    }
  }
  __syncthreads();
  for (int i = t; i < NBKT; i += 256)
    base[i] = h[i] ? atomicAdd(&gcur[i], h[i]) : 0;
  __syncthreads();
#pragma unroll
  for (int k = 0; k < 16; ++k)
    if (bkt[k] >= 0) stage[base[bkt[k]] + lp[k]] = rec[k];
}

// pass 3: one block per bucket -> offs, dinv, csr_src (LDS atomics only)
__global__ __launch_bounds__(256) void k_bplace(const int* __restrict__ stage,
                                                const int* __restrict__ bbase,
                                                int* __restrict__ offs,
                                                float* __restrict__ dinv,
                                                int* __restrict__ csr_src) {
  __shared__ int h[128];
  __shared__ int cur[128];
  int b = blockIdx.x;
  int t = threadIdx.x;
  int n0 = b * 128;
  int NN = NNODES - n0; if (NN > 128) NN = 128;
  int s0 = bbase[b], s1 = bbase[b + 1];
  int cnt = s1 - s0;
  if (t < 128) h[t] = 0;
  __syncthreads();
  for (int i = t; i < cnt; i += 256) {
    int rec = stage[s0 + i];
    atomicAdd(&h[rec >> 17], 1);
  }
  __syncthreads();
  if (t < 64) {
    int a = h[2 * t], c = h[2 * t + 1];
    int s = a + c;
    int x = s;
#pragma unroll
    for (int o = 1; o < 64; o <<= 1) {
      int y = __shfl_up(x, o, 64);
      if (t >= o) x += y;
    }
    int excl = s0 + x - s;
    cur[2 * t] = excl;
    cur[2 * t + 1] = excl + a;
    if (2 * t < NN) {
      offs[n0 + 2 * t] = excl;
      dinv[n0 + 2 * t] = rsqrtf((float)a + 1.0f);
    }
    if (2 * t + 1 < NN) {
      offs[n0 + 2 * t + 1] = excl + a;
      dinv[n0 + 2 * t + 1] = rsqrtf((float)c + 1.0f);
    }
  }
  if (b == NBKT - 1 && t == 0) offs[NNODES] = s1;
  __syncthreads();
  for (int i = t; i < cnt; i += 256) {
    int rec = stage[s0 + i];
    int pos = atomicAdd(&cur[rec >> 17], 1);
    csr_src[pos] = rec & 0x1FFFF;
  }
}

__device__ __forceinline__ void accp(f32x2 (&acc)[4], uint4 u, float w) {
  acc[0] += unpk(u.x) * w;
  acc[1] += unpk(u.y) * w;
  acc[2] += unpk(u.z) * w;
  acc[3] += unpk(u.w) * w;
}

// ---------- aggregation: one wave per node, packed fma, index prefetch ----------
// Input rows prescaled by dinv[src] (xs / hB). out[v] = dinv[v]*(edges + self).
// D=128: 16 lanes/row, 4 rows/instr; D=256: 32 lanes/row, 2 rows/instr.
// EPB edges per batch in flight; next batch's CSR indices prefetched during
// gathers (clamped indices make over-prefetch safe).
template <int D, int EPB>
__global__ __launch_bounds__(256) void k_agg(
    const unsigned short* __restrict__ hin, unsigned short* __restrict__ hout,
    const int* __restrict__ offs, const int* __restrict__ csr_src,
    const float* __restrict__ dinv) {
  constexpr int LPR = D / 8;    // lanes per row (16 B each)
  constexpr int R = 64 / LPR;   // rows per gather instr
  constexpr int NB = EPB / R;   // gather instrs per batch
  const int lane = threadIdx.x & 63;
  const int g = lane / LPR;     // row-group
  const int l = lane % LPR;     // lane within row
  const int v = (blockIdx.x * 256 + threadIdx.x) >> 6;
  if (v >= NNODES) return;

  float dv = dinv[v];
  const size_t vbase = (size_t)v * D + l * 8;
  uint4 su = *(const uint4*)(hin + vbase);
  f32x2 acc[4];
#pragma unroll
  for (int k = 0; k < 4; ++k) acc[k] = (f32x2)0.f;
  accp(acc, su, (g == 0) ? 1.f : 0.f);

  int b0 = offs[v];
  int n = offs[v + 1] - b0;
  if (n > 0) {
    int s[NB];
    float wg[NB];
#pragma unroll
    for (int j = 0; j < NB; ++j) {
      int e = j * R + g;
      int ec = (e < n) ? e : (n - 1);
      s[j] = csr_src[b0 + ec];
      wg[j] = (e < n) ? 1.f : 0.f;
    }
    for (int i = 0; i < n; i += EPB) {
      uint4 gu[NB];
#pragma unroll
      for (int j = 0; j < NB; ++j)
        gu[j] = *(const uint4*)(hin + (size_t)s[j] * D + l * 8);
      float wc[NB];
#pragma unroll
      for (int j = 0; j < NB; ++j) wc[j] = wg[j];
      int i2 = i + EPB;
#pragma unroll
      for (int j = 0; j < NB; ++j) {
        int e = i2 + j * R + g;
        int ec = (e < n) ? e : (n - 1);
        s[j] = csr_src[b0 + ec];
        wg[j] = (e < n) ? 1.f : 0.f;
      }
#pragma unroll
      for (int j = 0; j < NB; ++j) accp(acc, gu[j], wc[j]);
    }
  }
  float a8[8];
#pragma unroll
  for (int k = 0; k < 4; ++k) { a8[2 * k] = acc[k].x; a8[2 * k + 1] = acc[k].y; }
#pragma unroll
  for (int k = 0; k < 8; ++k) {
#pragma unroll
    for (int o = LPR; o < 64; o <<= 1) a8[k] += __shfl_xor(a8[k], o, 64);
  }
  if (g == 0) {
    uint4 ov;
    ov.x = (unsigned)f2bf(dv * a8[0]) | ((unsigned)f2bf(dv * a8[1]) << 16);
    ov.y = (unsigned)f2bf(dv * a8[2]) | ((unsigned)f2bf(dv * a8[3]) << 16);
    ov.z = (unsigned)f2bf(dv * a8[4]) | ((unsigned)f2bf(dv * a8[5]) << 16);
    ov.w = (unsigned)f2bf(dv * a8[6]) | ((unsigned)f2bf(dv * a8[7]) << 16);
    *(uint4*)(hout + vbase) = ov;
  }
}

// ---------- width-40 aggregation + bias + log_softmax (layer 3) ----------
// P prescaled by dinv[row]. One wave per node; 2 row-groups of 32 lanes
// (lanes 0..19 active), 8 edges per batch, index prefetch, packed fma.
__global__ __launch_bounds__(256) void k_agg40(
    const unsigned short* __restrict__ P, const int* __restrict__ offs,
    const int* __restrict__ csr_src, const float* __restrict__ dinv,
    const unsigned short* __restrict__ bias, float* __restrict__ outp) {
  const int lane = threadIdx.x & 63;
  const int g = lane >> 5, l = lane & 31;
  const bool act = l < 20;
  const int v = (blockIdx.x * 256 + threadIdx.x) >> 6;
  if (v >= NNODES) return;

  float dv = dinv[v];
  f32x2 a = (f32x2)0.f;
  if (act && g == 0) a = unpk(*(const unsigned*)(P + (size_t)v * 40 + l * 2));
  int b0 = offs[v];
  int n = offs[v + 1] - b0;
  if (n > 0) {
    int s[4];
    float wg[4];
#pragma unroll
    for (int j = 0; j < 4; ++j) {
      int e = j * 2 + g;
      int ec = (e < n) ? e : (n - 1);
      s[j] = csr_src[b0 + ec];
      wg[j] = (e < n) ? 1.f : 0.f;
    }
    for (int i = 0; i < n; i += 8) {
      unsigned gu[4];
#pragma unroll
      for (int j = 0; j < 4; ++j)
        gu[j] = act ? *(const unsigned*)(P + (size_t)s[j] * 40 + l * 2) : 0u;
      float wc[4];
#pragma unroll
      for (int j = 0; j < 4; ++j) wc[j] = wg[j];
      int i2 = i + 8;
#pragma unroll
      for (int j = 0; j < 4; ++j) {
        int e = i2 + j * 2 + g;
        int ec = (e < n) ? e : (n - 1);
        s[j] = csr_src[b0 + ec];
        wg[j] = (e < n) ? 1.f : 0.f;
      }
#pragma unroll
      for (int j = 0; j < 4; ++j) a += unpk(gu[j]) * wc[j];
    }
  }
  a.x += __shfl_xor(a.x, 32, 64);
  a.y += __shfl_xor(a.y, 32, 64);
  float a0 = 0.f, a1 = 0.f;
  if (act) {
    a0 = dv * a.x + bf2f((unsigned)bias[l * 2]);
    a1 = dv * a.y + bf2f((unsigned)bias[l * 2 + 1]);
  }
  float m = act ? fmaxf(a0, a1) : -1e30f;
#pragma unroll
  for (int o = 16; o > 0; o >>= 1) m = fmaxf(m, __shfl_xor(m, o, 32));
  float ss = act ? (expf(a0 - m) + expf(a1 - m)) : 0.f;
#pragma unroll
  for (int o = 16; o > 0; o >>= 1) ss += __shfl_xor(ss, o, 32);
  float ls = logf(ss) + m;
  if (act && g == 0) {
    float2 o2;
    o2.x = a0 - ls;
    o2.y = a1 - ls;
    *(float2*)(outp + (size_t)v * 160 + l * 2) = o2;
  }
}

// ---------- MFMA continue GEMM: out = relu(A[N,K] @ W[K,256] + b) [* dinv] ----------
template <int K, bool SCALE>
__global__ __launch_bounds__(256) void k_mlp_mfma(
    const unsigned short* __restrict__ A, const unsigned short* __restrict__ WT,
    const unsigned short* __restrict__ bias, unsigned short* __restrict__ out,
    const float* __restrict__ dinv) {
  __shared__ short As[128 * 40];
  __shared__ short Bs[128 * 40];
  const int t = threadIdx.x;
  const int lane = t & 63, wv = t >> 6;
  const int m0 = blockIdx.x * 128;
  const int c0 = blockIdx.y * 128;
  const int mw = (wv >> 1) * 64, nw = (wv & 1) * 64;
  const int lr = lane & 15, lq = lane >> 4;

  f32x4 acc[4][4];
#pragma unroll
  for (int i = 0; i < 4; ++i)
#pragma unroll
    for (int j = 0; j < 4; ++j) acc[i][j] = (f32x4)0.f;

  for (int kc = 0; kc < K; kc += 32) {
    __syncthreads();
#pragma unroll
    for (int it = 0; it < 2; ++it) {
      int idx = t + it * 256;
      int row = idx >> 2, seg = idx & 3;
      uint4 u = make_uint4(0, 0, 0, 0);
      int gr = m0 + row;
      if (gr < NNODES) u = *(const uint4*)(A + (size_t)gr * K + kc + seg * 8);
      *(uint4*)&As[row * 40 + seg * 8] = u;
      uint4 v = *(const uint4*)(WT + (size_t)(c0 + row) * K + kc + seg * 8);
      *(uint4*)&Bs[row * 40 + seg * 8] = v;
    }
    __syncthreads();
    bf16x8 af[4], bfr[4];
#pragma unroll
    for (int i = 0; i < 4; ++i)
      af[i] = *(const bf16x8*)&As[(mw + 16 * i + lr) * 40 + lq * 8];
#pragma unroll
    for (int j = 0; j < 4; ++j)
      bfr[j] = *(const bf16x8*)&Bs[(nw + 16 * j + lr) * 40 + lq * 8];
#pragma unroll
    for (int i = 0; i < 4; ++i)
#pragma unroll
      for (int j = 0; j < 4; ++j)
        acc[i][j] = __builtin_amdgcn_mfma_f32_16x16x32_bf16(af[i], bfr[j], acc[i][j], 0, 0, 0);
  }

  float bv[4];
#pragma unroll
  for (int j = 0; j < 4; ++j) bv[j] = bf2f((unsigned)bias[c0 + nw + 16 * j + lr]);
#pragma unroll
  for (int i = 0; i < 4; ++i) {
    int rbase = m0 + mw + 16 * i + lq * 4;
#pragma unroll
    for (int r = 0; r < 4; ++r) {
      int row = rbase + r;
      if (row < NNODES) {
        float s = SCALE ? dinv[row] : 1.f;
#pragma unroll
        for (int j = 0; j < 4; ++j) {
          int col = c0 + nw + 16 * j + lr;
          float v = fmaxf(acc[i][j][r] + bv[j], 0.f) * s;
          out[(size_t)row * 256 + col] = f2bf(v);
        }
      }
    }
  }
}

// ---------- MFMA exit GEMM (+ optional fused log_softmax) ----------
// 128-row tiles, hoisted B-panel in LDS (padded stride K+8).
template <int K, bool SOFTMAX>
__global__ __launch_bounds__(256) void k_exit_mfma(
    const unsigned short* __restrict__ A, const unsigned short* __restrict__ WT,
    const unsigned short* __restrict__ bias, float* __restrict__ outp,
    unsigned short* __restrict__ Pout, const float* __restrict__ dinv) {
  constexpr int KP = K + 8;
  __shared__ short As[128 * 40];
  __shared__ short Bs[48 * KP];
  const int t = threadIdx.x;
  const int lane = t & 63, wv = t >> 6;
  const int m0 = blockIdx.x * 128;
  const int mw = wv * 32;
  const int lr = lane & 15, lq = lane >> 4;

  for (int idx = t; idx < 48 * (K / 8); idx += 256) {
    int row = idx / (K / 8), seg = idx % (K / 8);
    uint4 w = *(const uint4*)(WT + (size_t)row * K + seg * 8);
    *(uint4*)&Bs[row * KP + seg * 8] = w;
  }

  f32x4 acc[2][3];
#pragma unroll
  for (int i = 0; i < 2; ++i)
#pragma unroll
    for (int j = 0; j < 3; ++j) acc[i][j] = (f32x4)0.f;

  for (int kc = 0; kc < K; kc += 32) {
    __syncthreads();
#pragma unroll
    for (int it = 0; it < 2; ++it) {
      int idx = t + it * 256;
      int row = idx >> 2, seg = idx & 3;
      uint4 u = make_uint4(0, 0, 0, 0);
      int gr = m0 + row;
      if (gr < NNODES) u = *(const uint4*)(A + (size_t)gr * K + kc + seg * 8);
      *(uint4*)&As[row * 40 + seg * 8] = u;
    }
    __syncthreads();
    bf16x8 af[2], bfr[3];
#pragma unroll
    for (int i = 0; i < 2; ++i)
      af[i] = *(const bf16x8*)&As[(mw + 16 * i + lr) * 40 + lq * 8];
#pragma unroll
    for (int j = 0; j < 3; ++j)
      bfr[j] = *(const bf16x8*)&Bs[(16 * j + lr) * KP + kc + lq * 8];
#pragma unroll
    for (int i = 0; i < 2; ++i)
#pragma unroll
      for (int j = 0; j < 3; ++j)
        acc[i][j] = __builtin_amdgcn_mfma_f32_16x16x32_bf16(af[i], bfr[j], acc[i][j], 0, 0, 0);
  }

  if (SOFTMAX) {
    float bv0 = bf2f((unsigned)bias[lr]);
    float bv1 = bf2f((unsigned)bias[16 + lr]);
    float bv2 = (lr < 8) ? bf2f((unsigned)bias[32 + lr]) : 0.f;
#pragma unroll
    for (int i = 0; i < 2; ++i) {
#pragma unroll
      for (int r = 0; r < 4; ++r) {
        int row = m0 + mw + 16 * i + lq * 4 + r;
        float v0 = acc[i][0][r] + bv0;
        float v1 = acc[i][1][r] + bv1;
        float v2 = (lr < 8) ? (acc[i][2][r] + bv2) : -1e30f;
        float m = fmaxf(fmaxf(v0, v1), v2);
#pragma unroll
        for (int o = 8; o > 0; o >>= 1) m = fmaxf(m, __shfl_xor(m, o, 16));
        float ss = expf(v0 - m) + expf(v1 - m) + ((lr < 8) ? expf(v2 - m) : 0.f);
#pragma unroll
        for (int o = 8; o > 0; o >>= 1) ss += __shfl_xor(ss, o, 16);
        float ls = logf(ss) + m;
        if (row < NNODES) {
          outp[(size_t)row * 160 + lr] = v0 - ls;
          outp[(size_t)row * 160 + 16 + lr] = v1 - ls;
          if (lr < 8) outp[(size_t)row * 160 + 32 + lr] = v2 - ls;
        }
      }
    }
  } else {
#pragma unroll
    for (int i = 0; i < 2; ++i) {
#pragma unroll
      for (int r = 0; r < 4; ++r) {
        int row = m0 + mw + 16 * i + lq * 4 + r;
        if (row < NNODES) {
          float s = dinv[row];
          Pout[(size_t)row * 40 + lr] = f2bf(acc[i][0][r] * s);
          Pout[(size_t)row * 40 + 16 + lr] = f2bf(acc[i][1][r] * s);
          if (lr < 8) Pout[(size_t)row * 40 + 32 + lr] = f2bf(acc[i][2][r] * s);
        }
      }
    }
  }
}

// ---------- launch ----------
extern "C" void kernel_launch(void* const* d_in, const int* in_sizes, int n_in,
                              void* d_out, int out_size, void* d_ws, size_t ws_size,
                              hipStream_t stream) {
  const void* x_raw   = d_in[0];
  const int* ei       = (const int*)d_in[1];
  float* out          = (float*)d_out;

  char* ws = (char*)d_ws;
  int*   flags    = (int*)(ws + 0);
  int*   bcnt     = (int*)(ws + 4096);      // 782 ints
  int*   gcur     = (int*)(ws + 8192);      // 782 ints
  int*   bbase    = (int*)(ws + 12288);     // 783 ints
  float* dinv     = (float*)(ws + 524288);  // 400 KB
  int*   offs     = (int*)(ws + 1048576);   // 400 KB + 4
  int*   csr_src  = (int*)(ws + 2097152);   // 6.4 MB
  int*   stage    = (int*)(ws + 8650752);   // 6.4 MB staged recs
  unsigned short* xb = (unsigned short*)(ws + 16777216);   // N*128 bf16 (reused as P)
  unsigned short* wb = (unsigned short*)(ws + 45088768);   // weights
  unsigned short* hA = (unsigned short*)(ws + 48234496);   // N*256 bf16
  unsigned short* hB = (unsigned short*)(ws + 100663296);  // N*256 bf16
  unsigned short* xs = hB;  // prescaled x aliases hB (dead until mlp<128> writes it)
  unsigned short* P  = xb;

  unsigned short* Wc0 = wb + 0;
  unsigned short* bc0 = wb + 32768;
  unsigned short* Wc1 = wb + 33024;
  unsigned short* bc1 = wb + 98560;
  unsigned short* We0 = wb + 98816;
  unsigned short* be0 = wb + 103936;
  unsigned short* We1 = wb + 103976;
  unsigned short* be1 = wb + 109096;
  unsigned short* We2 = wb + 109136;
  unsigned short* be2 = wb + 119376;
  unsigned short* We3 = wb + 119416;
  unsigned short* be3 = wb + 129656;
  unsigned short* WTc0  = wb + 131072;  // 256 x 128
  unsigned short* WTc1  = wb + 163840;  // 256 x 256
  unsigned short* WT40e0 = wb + 229376; // 48 x 128
  unsigned short* WT40e1 = wb + 235520; // 48 x 128
  unsigned short* WT40e2 = wb + 241664; // 48 x 256
  unsigned short* WT40e3 = wb + 253952; // 48 x 256

  dim3 B(256);
  // probe dtypes + zero bucket counters
  k_probe<<<dim3(1), B, 0, stream>>>((const unsigned*)x_raw, ei, flags, bcnt);

  // bucketed CSR build first (produces dinv for the prescaled cvt)
  k_bcnt<<<dim3(391), B, 0, stream>>>(ei, bcnt, flags);
  k_bscan2<<<dim3(1), dim3(64), 0, stream>>>(bcnt, bbase, gcur);
  k_bstage<<<dim3(391), B, 0, stream>>>(ei, gcur, stage, flags);
  k_bplace<<<dim3(NBKT), B, 0, stream>>>(stage, bbase, offs, dinv, csr_src);

  CvtParams p;
  const int srcIdx[13] = {0, 2, 3, 4, 5, 8, 9, 10, 11, 12, 13, 14, 15};
  unsigned short* dsts[13] = {xb, Wc0, bc0, Wc1, bc1, We0, be0, We1, be1, We2, be2, We3, be3};
  const int ns[13] = {NNODES * 128, 128 * 256, 256, 256 * 256, 256,
                      128 * 40, 40, 128 * 40, 40, 256 * 40, 40, 256 * 40, 40};
  for (int i = 0; i < 13; ++i) { p.src[i] = d_in[srcIdx[i]]; p.dst[i] = dsts[i]; p.n[i] = ns[i]; }
  k_cvt<<<dim3(1024, 13), B, 0, stream>>>(p, flags, dinv, xs);
  k_wprep<<<dim3(256, 6), B, 0, stream>>>(Wc0, WTc0, Wc1, WTc1, We0, WT40e0,
                                          We1, WT40e1, We2, WT40e2, We3, WT40e3);

  // layer 0: on x
  k_exit_mfma<128, true><<<dim3(782), B, 0, stream>>>(xb, WT40e0, be0, out + 0 * 40, nullptr, dinv);
  // h1 = agg(xs): prescaled input, 16-edge batches
  k_agg<128, 16><<<dim3(25000), B, 0, stream>>>(xs, hA, offs, csr_src, dinv);
  k_exit_mfma<128, true><<<dim3(782), B, 0, stream>>>(hA, WT40e1, be1, out + 1 * 40, nullptr, dinv);
  // hB = relu(h1 Wc0 + bc0) * dinv   (prescaled for next agg; overwrites xs)
  k_mlp_mfma<128, true><<<dim3(782, 2), B, 0, stream>>>(hA, WTc0, bc0, hB, dinv);
  // h2 = agg(hB): prescaled input, 8-edge batches
  k_agg<256, 8><<<dim3(25000), B, 0, stream>>>(hB, hA, offs, csr_src, dinv);
  k_exit_mfma<256, true><<<dim3(782), B, 0, stream>>>(hA, WT40e2, be2, out + 2 * 40, nullptr, dinv);
  k_mlp_mfma<256, false><<<dim3(782, 2), B, 0, stream>>>(hA, WTc1, bc1, hB, nullptr);
  // layer 3 push-through: P = (hc2 @ We3) * dinv
  k_exit_mfma<256, false><<<dim3(782), B, 0, stream>>>(hB, WT40e3, nullptr, nullptr, P, dinv);
  k_agg40<<<dim3(25000), B, 0, stream>>>(P, offs, csr_src, dinv, be3, out + 3 * 40);
}

// Round 6
// 622.831 us; speedup vs baseline: 1.0224x; 1.0224x over previous
//
#include <hip/hip_runtime.h>

#define NNODES 100000
#define NEDGES 1600000
#define NBKT 782          // buckets of 128 nodes: 782*128 = 100096 >= NNODES

typedef __attribute__((ext_vector_type(8))) short bf16x8;
typedef __attribute__((ext_vector_type(4))) float f32x4;
typedef __attribute__((ext_vector_type(2))) float f32x2;

// ---------- bf16 helpers ----------
__device__ __forceinline__ float bf2f(unsigned v) {
  union { unsigned u; float f; } x; x.u = v << 16; return x.f;
}
__device__ __forceinline__ unsigned short f2bf(float f) {
  union { float f; unsigned u; } x; x.f = f;
  unsigned r = x.u + 0x7fffu + ((x.u >> 16) & 1u);
  return (unsigned short)(r >> 16);
}
__device__ __forceinline__ f32x2 unpk(unsigned u) {
  union { unsigned q; float f; } lo, hi;
  lo.q = u << 16; hi.q = u & 0xffff0000u;
  f32x2 r; r.x = lo.f; r.y = hi.f; return r;
}
__device__ __forceinline__ unsigned short ldcv(const void* p, int i, int f32) {
  return f32 ? f2bf(((const float*)p)[i]) : ((const unsigned short*)p)[i];
}
// per-wave i64 self-detection: high words of int64 node ids are all zero
__device__ __forceinline__ int detect_i64(const int* __restrict__ ei) {
  int lane = threadIdx.x & 63;
  int hv = ei[2 * lane + 1];
  unsigned long long nz = __ballot(hv != 0);
  return (__popcll(nz) < 4) ? 1 : 0;
}
__device__ __forceinline__ int edge_at(const int* __restrict__ ei, int j, int i64) {
  return i64 ? ei[2 * j] : ei[j];
}

__global__ void k_zero(int* __restrict__ p, int n) {
  int v = blockIdx.x * blockDim.x + threadIdx.x;
  if (v < n) p[v] = 0;
}

// ---------- bucketed CSR build (no global per-edge atomics) ----------
// Bucket b = dst >> 7 covers nodes [128b, 128b+128). Record: (dstloc<<17)|src.

// pass 1: per-block LDS histogram; block 0 also probes x dtype -> flags[0]
__global__ __launch_bounds__(256) void k_bcnt(const int* __restrict__ ei,
                                              int* __restrict__ bcnt,
                                              const unsigned* __restrict__ xw,
                                              int* __restrict__ flags) {
  __shared__ int h[NBKT];
  __shared__ int cF;
  int t = threadIdx.x;
  for (int i = t; i < NBKT; i += 256) h[i] = 0;
  if (blockIdx.x == 0 && t == 0) cF = 0;
  __syncthreads();
  if (blockIdx.x == 0) {
    int hf = 0;
    for (int i = t; i < 2048; i += 256) {
      unsigned lo = xw[i] & 0xffffu;
      unsigned e = (lo >> 7) & 0xffu;
      if (e >= 0xC0u) hf++;
    }
    atomicAdd(&cF, hf);
  }
  int i64 = detect_i64(ei);
  int e0 = blockIdx.x * 4096;
#pragma unroll
  for (int k = 0; k < 16; ++k) {
    int e = e0 + t + k * 256;
    if (e < NEDGES) {
      int d = edge_at(ei, NEDGES + e, i64);
      if ((unsigned)d < NNODES) atomicAdd(&h[d >> 7], 1);
    }
  }
  __syncthreads();
  for (int i = t; i < NBKT; i += 256)
    if (h[i]) atomicAdd(&bcnt[i], h[i]);
  if (blockIdx.x == 0 && t == 0) flags[0] = (cF > 32) ? 1 : 0;
}

// scan 782 bucket counts -> bbase[0..782], init gcur
__global__ void k_bscan2(const int* __restrict__ bcnt, int* __restrict__ bbase,
                         int* __restrict__ gcur) {
  int l = threadIdx.x;  // 64 lanes
  int v[13];
  int s = 0;
#pragma unroll
  for (int k = 0; k < 13; ++k) {
    int j = l * 13 + k;
    v[k] = (j < NBKT) ? bcnt[j] : 0;
    s += v[k];
  }
  int x = s;
#pragma unroll
  for (int o = 1; o < 64; o <<= 1) {
    int y = __shfl_up(x, o, 64);
    if (l >= o) x += y;
  }
  int excl = x - s;
#pragma unroll
  for (int k = 0; k < 13; ++k) {
    int j = l * 13 + k;
    if (j < NBKT) { bbase[j] = excl; gcur[j] = excl; }
    excl += v[k];
  }
  if (l == 63) bbase[NBKT] = x;
}

// pass 2: stage records bucket-contiguously (block-aggregated reservations)
__global__ __launch_bounds__(256) void k_bstage(const int* __restrict__ ei,
                                                int* __restrict__ gcur,
                                                int* __restrict__ stage) {
  __shared__ int h[NBKT];
  __shared__ int base[NBKT];
  int t = threadIdx.x;
  for (int i = t; i < NBKT; i += 256) h[i] = 0;
  __syncthreads();
  int i64 = detect_i64(ei);
  int e0 = blockIdx.x * 4096;
  int bkt[16], lp[16], rec[16];
#pragma unroll
  for (int k = 0; k < 16; ++k) {
    bkt[k] = -1;
    int e = e0 + t + k * 256;
    if (e < NEDGES) {
      int d = edge_at(ei, NEDGES + e, i64);
      if ((unsigned)d < NNODES) {
        int s = edge_at(ei, e, i64);
        if ((unsigned)s >= NNODES) s = NNODES - 1;
        bkt[k] = d >> 7;
        rec[k] = ((d & 127) << 17) | s;
        lp[k] = atomicAdd(&h[bkt[k]], 1);
      }
    }
  }
  __syncthreads();
  for (int i = t; i < NBKT; i += 256)
    base[i] = h[i] ? atomicAdd(&gcur[i], h[i]) : 0;
  __syncthreads();
#pragma unroll
  for (int k = 0; k < 16; ++k)
    if (bkt[k] >= 0) stage[base[bkt[k]] + lp[k]] = rec[k];
}

// pass 3: one block per bucket -> offs, dinv, csr_src (LDS atomics only)
__global__ __launch_bounds__(256) void k_bplace(const int* __restrict__ stage,
                                                const int* __restrict__ bbase,
                                                int* __restrict__ offs,
                                                float* __restrict__ dinv,
                                                int* __restrict__ csr_src) {
  __shared__ int h[128];
  __shared__ int cur[128];
  int b = blockIdx.x;
  int t = threadIdx.x;
  int n0 = b * 128;
  int NN = NNODES - n0; if (NN > 128) NN = 128;
  int s0 = bbase[b], s1 = bbase[b + 1];
  int cnt = s1 - s0;
  if (t < 128) h[t] = 0;
  __syncthreads();
  for (int i = t; i < cnt; i += 256) {
    int rec = stage[s0 + i];
    atomicAdd(&h[rec >> 17], 1);
  }
  __syncthreads();
  if (t < 64) {
    int a = h[2 * t], c = h[2 * t + 1];
    int s = a + c;
    int x = s;
#pragma unroll
    for (int o = 1; o < 64; o <<= 1) {
      int y = __shfl_up(x, o, 64);
      if (t >= o) x += y;
    }
    int excl = s0 + x - s;
    cur[2 * t] = excl;
    cur[2 * t + 1] = excl + a;
    if (2 * t < NN) {
      offs[n0 + 2 * t] = excl;
      dinv[n0 + 2 * t] = rsqrtf((float)a + 1.0f);
    }
    if (2 * t + 1 < NN) {
      offs[n0 + 2 * t + 1] = excl + a;
      dinv[n0 + 2 * t + 1] = rsqrtf((float)c + 1.0f);
    }
  }
  if (b == NBKT - 1 && t == 0) offs[NNODES] = s1;
  __syncthreads();
  for (int i = t; i < cnt; i += 256) {
    int rec = stage[s0 + i];
    int pos = atomicAdd(&cur[rec >> 17], 1);
    csr_src[pos] = rec & 0x1FFFF;
  }
}

// ---------- canonicalize + weight prep, one dispatch ----------
// y=0: x -> xb and xs = x*dinv[row]; y=1..6: biases; y=7: raw-W transposes.
struct CvtP {
  const void* src[7];
  unsigned short* dst[7];
  int n[7];
  const void* W[6];           // raw Wc0, Wc1, We0, We1, We2, We3
  unsigned short* WT[6];      // WTc0, WTc1, WT40e0..WT40e3
};

__global__ void k_cvt(CvtP p, const int* __restrict__ flags,
                      const float* __restrict__ dinv, unsigned short* __restrict__ xs) {
  int a = blockIdx.y;
  int f32 = flags[0];
  if (a < 7) {
    int n = p.n[a];
    const float* sf = (const float*)p.src[a];
    const unsigned short* sb = (const unsigned short*)p.src[a];
    unsigned short* d = p.dst[a];
    for (int i = blockIdx.x * blockDim.x + threadIdx.x; i < n; i += gridDim.x * blockDim.x) {
      if (a == 0) {
        float v = f32 ? sf[i] : bf2f((unsigned)sb[i]);
        d[i] = f32 ? f2bf(v) : sb[i];
        xs[i] = f2bf(v * dinv[i >> 7]);
      } else {
        d[i] = f32 ? f2bf(sf[i]) : sb[i];
      }
    }
  } else {
    int g = blockIdx.x * 256 + threadIdx.x;
    if (g < 32768) {                       // Wc0[128,256] -> WTc0[256,128]
      int k = g >> 8, c = g & 255;
      p.WT[0][c * 128 + k] = ldcv(p.W[0], g, f32);
    } else if (g < 98304) {                // Wc1[256,256] -> WTc1[256,256]
      int l = g - 32768; int k = l >> 8, c = l & 255;
      p.WT[1][c * 256 + k] = ldcv(p.W[1], l, f32);
    } else if (g < 104448) {               // We0[128,40] -> WT40e0[48,128]
      int l = g - 98304; int c = l >> 7, k = l & 127;
      p.WT[2][l] = (c < 40) ? ldcv(p.W[2], k * 40 + c, f32) : (unsigned short)0;
    } else if (g < 110592) {               // We1
      int l = g - 104448; int c = l >> 7, k = l & 127;
      p.WT[3][l] = (c < 40) ? ldcv(p.W[3], k * 40 + c, f32) : (unsigned short)0;
    } else if (g < 122880) {               // We2[256,40] -> WT40e2[48,256]
      int l = g - 110592; int c = l >> 8, k = l & 255;
      p.WT[4][l] = (c < 40) ? ldcv(p.W[4], k * 40 + c, f32) : (unsigned short)0;
    } else if (g < 135168) {               // We3
      int l = g - 122880; int c = l >> 8, k = l & 255;
      p.WT[5][l] = (c < 40) ? ldcv(p.W[5], k * 40 + c, f32) : (unsigned short)0;
    }
  }
}

__device__ __forceinline__ void accp(f32x2 (&acc)[4], uint4 u, float w) {
  acc[0] += unpk(u.x) * w;
  acc[1] += unpk(u.y) * w;
  acc[2] += unpk(u.z) * w;
  acc[3] += unpk(u.w) * w;
}

// ---------- aggregation: one wave per node, packed fma, index prefetch ----------
template <int D, int EPB>
__global__ __launch_bounds__(256) void k_agg(
    const unsigned short* __restrict__ hin, unsigned short* __restrict__ hout,
    const int* __restrict__ offs, const int* __restrict__ csr_src,
    const float* __restrict__ dinv) {
  constexpr int LPR = D / 8;    // lanes per row (16 B each)
  constexpr int R = 64 / LPR;   // rows per gather instr
  constexpr int NB = EPB / R;   // gather instrs per batch
  const int lane = threadIdx.x & 63;
  const int g = lane / LPR;
  const int l = lane % LPR;
  const int v = (blockIdx.x * 256 + threadIdx.x) >> 6;
  if (v >= NNODES) return;

  float dv = dinv[v];
  const size_t vbase = (size_t)v * D + l * 8;
  uint4 su = *(const uint4*)(hin + vbase);
  f32x2 acc[4];
#pragma unroll
  for (int k = 0; k < 4; ++k) acc[k] = (f32x2)0.f;
  accp(acc, su, (g == 0) ? 1.f : 0.f);

  int b0 = offs[v];
  int n = offs[v + 1] - b0;
  if (n > 0) {
    int s[NB];
    float wg[NB];
#pragma unroll
    for (int j = 0; j < NB; ++j) {
      int e = j * R + g;
      int ec = (e < n) ? e : (n - 1);
      s[j] = csr_src[b0 + ec];
      wg[j] = (e < n) ? 1.f : 0.f;
    }
    for (int i = 0; i < n; i += EPB) {
      uint4 gu[NB];
#pragma unroll
      for (int j = 0; j < NB; ++j)
        gu[j] = *(const uint4*)(hin + (size_t)s[j] * D + l * 8);
      float wc[NB];
#pragma unroll
      for (int j = 0; j < NB; ++j) wc[j] = wg[j];
      int i2 = i + EPB;
#pragma unroll
      for (int j = 0; j < NB; ++j) {
        int e = i2 + j * R + g;
        int ec = (e < n) ? e : (n - 1);
        s[j] = csr_src[b0 + ec];
        wg[j] = (e < n) ? 1.f : 0.f;
      }
#pragma unroll
      for (int j = 0; j < NB; ++j) accp(acc, gu[j], wc[j]);
    }
  }
  float a8[8];
#pragma unroll
  for (int k = 0; k < 4; ++k) { a8[2 * k] = acc[k].x; a8[2 * k + 1] = acc[k].y; }
#pragma unroll
  for (int k = 0; k < 8; ++k) {
#pragma unroll
    for (int o = LPR; o < 64; o <<= 1) a8[k] += __shfl_xor(a8[k], o, 64);
  }
  if (g == 0) {
    uint4 ov;
    ov.x = (unsigned)f2bf(dv * a8[0]) | ((unsigned)f2bf(dv * a8[1]) << 16);
    ov.y = (unsigned)f2bf(dv * a8[2]) | ((unsigned)f2bf(dv * a8[3]) << 16);
    ov.z = (unsigned)f2bf(dv * a8[4]) | ((unsigned)f2bf(dv * a8[5]) << 16);
    ov.w = (unsigned)f2bf(dv * a8[6]) | ((unsigned)f2bf(dv * a8[7]) << 16);
    *(uint4*)(hout + vbase) = ov;
  }
}

// ---------- width-40 aggregation + bias + log_softmax (layer 3) ----------
__global__ __launch_bounds__(256) void k_agg40(
    const unsigned short* __restrict__ P, const int* __restrict__ offs,
    const int* __restrict__ csr_src, const float* __restrict__ dinv,
    const unsigned short* __restrict__ bias, float* __restrict__ outp) {
  const int lane = threadIdx.x & 63;
  const int g = lane >> 5, l = lane & 31;
  const bool act = l < 20;
  const int v = (blockIdx.x * 256 + threadIdx.x) >> 6;
  if (v >= NNODES) return;

  float dv = dinv[v];
  f32x2 a = (f32x2)0.f;
  if (act && g == 0) a = unpk(*(const unsigned*)(P + (size_t)v * 40 + l * 2));
  int b0 = offs[v];
  int n = offs[v + 1] - b0;
  if (n > 0) {
    int s[4];
    float wg[4];
#pragma unroll
    for (int j = 0; j < 4; ++j) {
      int e = j * 2 + g;
      int ec = (e < n) ? e : (n - 1);
      s[j] = csr_src[b0 + ec];
      wg[j] = (e < n) ? 1.f : 0.f;
    }
    for (int i = 0; i < n; i += 8) {
      unsigned gu[4];
#pragma unroll
      for (int j = 0; j < 4; ++j)
        gu[j] = act ? *(const unsigned*)(P + (size_t)s[j] * 40 + l * 2) : 0u;
      float wc[4];
#pragma unroll
      for (int j = 0; j < 4; ++j) wc[j] = wg[j];
      int i2 = i + 8;
#pragma unroll
      for (int j = 0; j < 4; ++j) {
        int e = i2 + j * 2 + g;
        int ec = (e < n) ? e : (n - 1);
        s[j] = csr_src[b0 + ec];
        wg[j] = (e < n) ? 1.f : 0.f;
      }
#pragma unroll
      for (int j = 0; j < 4; ++j) a += unpk(gu[j]) * wc[j];
    }
  }
  a.x += __shfl_xor(a.x, 32, 64);
  a.y += __shfl_xor(a.y, 32, 64);
  float a0 = 0.f, a1 = 0.f;
  if (act) {
    a0 = dv * a.x + bf2f((unsigned)bias[l * 2]);
    a1 = dv * a.y + bf2f((unsigned)bias[l * 2 + 1]);
  }
  float m = act ? fmaxf(a0, a1) : -1e30f;
#pragma unroll
  for (int o = 16; o > 0; o >>= 1) m = fmaxf(m, __shfl_xor(m, o, 32));
  float ss = act ? (expf(a0 - m) + expf(a1 - m)) : 0.f;
#pragma unroll
  for (int o = 16; o > 0; o >>= 1) ss += __shfl_xor(ss, o, 32);
  float ls = logf(ss) + m;
  if (act && g == 0) {
    float2 o2;
    o2.x = a0 - ls;
    o2.y = a1 - ls;
    *(float2*)(outp + (size_t)v * 160 + l * 2) = o2;
  }
}

// ---------- GEMM bodies on caller-provided LDS ----------
// mlp: out = relu(A[N,K] @ W[K,256] + b) [* dinv]; 128x128 tile at (m0,c0)
template <int K, bool SCALE>
__device__ __forceinline__ void mlp_body(
    char* smem, int m0, int c0,
    const unsigned short* __restrict__ A, const unsigned short* __restrict__ WT,
    const unsigned short* __restrict__ bias, unsigned short* __restrict__ out,
    const float* __restrict__ dinv) {
  short* As = (short*)smem;             // 128*40
  short* Bs = (short*)(smem + 10240);   // 128*40
  const int t = threadIdx.x;
  const int lane = t & 63, wv = t >> 6;
  const int mw = (wv >> 1) * 64, nw = (wv & 1) * 64;
  const int lr = lane & 15, lq = lane >> 4;

  f32x4 acc[4][4];
#pragma unroll
  for (int i = 0; i < 4; ++i)
#pragma unroll
    for (int j = 0; j < 4; ++j) acc[i][j] = (f32x4)0.f;

  for (int kc = 0; kc < K; kc += 32) {
    __syncthreads();
#pragma unroll
    for (int it = 0; it < 2; ++it) {
      int idx = t + it * 256;
      int row = idx >> 2, seg = idx & 3;
      uint4 u = make_uint4(0, 0, 0, 0);
      int gr = m0 + row;
      if (gr < NNODES) u = *(const uint4*)(A + (size_t)gr * K + kc + seg * 8);
      *(uint4*)&As[row * 40 + seg * 8] = u;
      uint4 v = *(const uint4*)(WT + (size_t)(c0 + row) * K + kc + seg * 8);
      *(uint4*)&Bs[row * 40 + seg * 8] = v;
    }
    __syncthreads();
    bf16x8 af[4], bfr[4];
#pragma unroll
    for (int i = 0; i < 4; ++i)
      af[i] = *(const bf16x8*)&As[(mw + 16 * i + lr) * 40 + lq * 8];
#pragma unroll
    for (int j = 0; j < 4; ++j)
      bfr[j] = *(const bf16x8*)&Bs[(nw + 16 * j + lr) * 40 + lq * 8];
#pragma unroll
    for (int i = 0; i < 4; ++i)
#pragma unroll
      for (int j = 0; j < 4; ++j)
        acc[i][j] = __builtin_amdgcn_mfma_f32_16x16x32_bf16(af[i], bfr[j], acc[i][j], 0, 0, 0);
  }

  float bv[4];
#pragma unroll
  for (int j = 0; j < 4; ++j) bv[j] = bf2f((unsigned)bias[c0 + nw + 16 * j + lr]);
#pragma unroll
  for (int i = 0; i < 4; ++i) {
    int rbase = m0 + mw + 16 * i + lq * 4;
#pragma unroll
    for (int r = 0; r < 4; ++r) {
      int row = rbase + r;
      if (row < NNODES) {
        float s = SCALE ? dinv[row] : 1.f;
#pragma unroll
        for (int j = 0; j < 4; ++j) {
          int col = c0 + nw + 16 * j + lr;
          float v = fmaxf(acc[i][j][r] + bv[j], 0.f) * s;
          out[(size_t)row * 256 + col] = f2bf(v);
        }
      }
    }
  }
}

// exit: (A@We) 128-row tile; SOFTMAX -> f32 log-softmax rows, else P*dinv bf16
template <int K, bool SOFTMAX>
__device__ __forceinline__ void exit_body(
    char* smem, int m0,
    const unsigned short* __restrict__ A, const unsigned short* __restrict__ WT,
    const unsigned short* __restrict__ bias, float* __restrict__ outp,
    unsigned short* __restrict__ Pout, const float* __restrict__ dinv) {
  constexpr int KP = K + 8;
  short* As = (short*)smem;             // 128*40
  short* Bs = (short*)(smem + 10240);   // 48*KP
  const int t = threadIdx.x;
  const int lane = t & 63, wv = t >> 6;
  const int mw = wv * 32;
  const int lr = lane & 15, lq = lane >> 4;

  for (int idx = t; idx < 48 * (K / 8); idx += 256) {
    int row = idx / (K / 8), seg = idx % (K / 8);
    uint4 w = *(const uint4*)(WT + (size_t)row * K + seg * 8);
    *(uint4*)&Bs[row * KP + seg * 8] = w;
  }

  f32x4 acc[2][3];
#pragma unroll
  for (int i = 0; i < 2; ++i)
#pragma unroll
    for (int j = 0; j < 3; ++j) acc[i][j] = (f32x4)0.f;

  for (int kc = 0; kc < K; kc += 32) {
    __syncthreads();
#pragma unroll
    for (int it = 0; it < 2; ++it) {
      int idx = t + it * 256;
      int row = idx >> 2, seg = idx & 3;
      uint4 u = make_uint4(0, 0, 0, 0);
      int gr = m0 + row;
      if (gr < NNODES) u = *(const uint4*)(A + (size_t)gr * K + kc + seg * 8);
      *(uint4*)&As[row * 40 + seg * 8] = u;
    }
    __syncthreads();
    bf16x8 af[2], bfr[3];
#pragma unroll
    for (int i = 0; i < 2; ++i)
      af[i] = *(const bf16x8*)&As[(mw + 16 * i + lr) * 40 + lq * 8];
#pragma unroll
    for (int j = 0; j < 3; ++j)
      bfr[j] = *(const bf16x8*)&Bs[(16 * j + lr) * KP + kc + lq * 8];
#pragma unroll
    for (int i = 0; i < 2; ++i)
#pragma unroll
      for (int j = 0; j < 3; ++j)
        acc[i][j] = __builtin_amdgcn_mfma_f32_16x16x32_bf16(af[i], bfr[j], acc[i][j], 0, 0, 0);
  }

  if (SOFTMAX) {
    float bv0 = bf2f((unsigned)bias[lr]);
    float bv1 = bf2f((unsigned)bias[16 + lr]);
    float bv2 = (lr < 8) ? bf2f((unsigned)bias[32 + lr]) : 0.f;
#pragma unroll
    for (int i = 0; i < 2; ++i) {
#pragma unroll
      for (int r = 0; r < 4; ++r) {
        int row = m0 + mw + 16 * i + lq * 4 + r;
        float v0 = acc[i][0][r] + bv0;
        float v1 = acc[i][1][r] + bv1;
        float v2 = (lr < 8) ? (acc[i][2][r] + bv2) : -1e30f;
        float m = fmaxf(fmaxf(v0, v1), v2);
#pragma unroll
        for (int o = 8; o > 0; o >>= 1) m = fmaxf(m, __shfl_xor(m, o, 16));
        float ss = expf(v0 - m) + expf(v1 - m) + ((lr < 8) ? expf(v2 - m) : 0.f);
#pragma unroll
        for (int o = 8; o > 0; o >>= 1) ss += __shfl_xor(ss, o, 16);
        float ls = logf(ss) + m;
        if (row < NNODES) {
          outp[(size_t)row * 160 + lr] = v0 - ls;
          outp[(size_t)row * 160 + 16 + lr] = v1 - ls;
          if (lr < 8) outp[(size_t)row * 160 + 32 + lr] = v2 - ls;
        }
      }
    }
  } else {
#pragma unroll
    for (int i = 0; i < 2; ++i) {
#pragma unroll
      for (int r = 0; r < 4; ++r) {
        int row = m0 + mw + 16 * i + lq * 4 + r;
        if (row < NNODES) {
          float s = dinv[row];
          Pout[(size_t)row * 40 + lr] = f2bf(acc[i][0][r] * s);
          Pout[(size_t)row * 40 + 16 + lr] = f2bf(acc[i][1][r] * s);
          if (lr < 8) Pout[(size_t)row * 40 + 32 + lr] = f2bf(acc[i][2][r] * s);
        }
      }
    }
  }
}

// ---------- kernels wrapping the bodies ----------
template <int K> struct ExitSM { static constexpr int B = 10240 + 48 * (K + 8) * 2; };

__global__ __launch_bounds__(256) void k_exit0(
    const unsigned short* __restrict__ A, const unsigned short* __restrict__ WT,
    const unsigned short* __restrict__ bias, float* __restrict__ outp,
    const float* __restrict__ dinv) {
  __shared__ __align__(16) char smem[ExitSM<128>::B];
  exit_body<128, true>(smem, blockIdx.x * 128, A, WT, bias, outp, nullptr, dinv);
}

__global__ __launch_bounds__(256) void k_exit3(
    const unsigned short* __restrict__ A, const unsigned short* __restrict__ WT,
    unsigned short* __restrict__ Pout, const float* __restrict__ dinv) {
  __shared__ __align__(16) char smem[ExitSM<256>::B];
  exit_body<256, false>(smem, blockIdx.x * 128, A, WT, nullptr, nullptr, Pout, dinv);
}

// heterogeneous: blocks [0,1564) mlp (128x128 tiles, 2 col-halves);
// blocks [1564, 2346) exit+softmax. Both read the same A.
template <int K, bool MLPSCALE>
__global__ __launch_bounds__(256) void k_exit_mlp(
    const unsigned short* __restrict__ A,
    const unsigned short* __restrict__ WTmlp, const unsigned short* __restrict__ bmlp,
    unsigned short* __restrict__ outmlp,
    const unsigned short* __restrict__ WTex, const unsigned short* __restrict__ bex,
    float* __restrict__ outp, const float* __restrict__ dinv) {
  constexpr int SM = (ExitSM<K>::B > 20480) ? ExitSM<K>::B : 20480;
  __shared__ __align__(16) char smem[SM];
  int bid = blockIdx.x;
  if (bid < 1564) {
    mlp_body<K, MLPSCALE>(smem, (bid >> 1) * 128, (bid & 1) * 128, A, WTmlp, bmlp, outmlp, dinv);
  } else {
    exit_body<K, true>(smem, (bid - 1564) * 128, A, WTex, bex, outp, nullptr, dinv);
  }
}

// ---------- launch ----------
extern "C" void kernel_launch(void* const* d_in, const int* in_sizes, int n_in,
                              void* d_out, int out_size, void* d_ws, size_t ws_size,
                              hipStream_t stream) {
  const void* x_raw   = d_in[0];
  const int* ei       = (const int*)d_in[1];
  float* out          = (float*)d_out;

  char* ws = (char*)d_ws;
  int*   flags    = (int*)(ws + 0);
  int*   bcnt     = (int*)(ws + 4096);      // 782 ints
  int*   gcur     = (int*)(ws + 8192);      // 782 ints
  int*   bbase    = (int*)(ws + 12288);     // 783 ints
  float* dinv     = (float*)(ws + 524288);  // 400 KB
  int*   offs     = (int*)(ws + 1048576);   // 400 KB + 4
  int*   csr_src  = (int*)(ws + 2097152);   // 6.4 MB
  int*   stage    = (int*)(ws + 8650752);   // 6.4 MB staged recs
  unsigned short* xb = (unsigned short*)(ws + 16777216);   // N*128 bf16 (reused as P)
  unsigned short* wb = (unsigned short*)(ws + 45088768);   // weights
  unsigned short* hA = (unsigned short*)(ws + 48234496);   // N*256 bf16
  unsigned short* hB = (unsigned short*)(ws + 100663296);  // N*256 bf16
  unsigned short* xs = hB;  // prescaled x aliases hB (dead until mlp<128> writes it)
  unsigned short* P  = xb;

  unsigned short* bc0 = wb + 32768;
  unsigned short* bc1 = wb + 98560;
  unsigned short* be0 = wb + 103936;
  unsigned short* be1 = wb + 109096;
  unsigned short* be2 = wb + 119376;
  unsigned short* be3 = wb + 129656;
  unsigned short* WTc0  = wb + 131072;  // 256 x 128
  unsigned short* WTc1  = wb + 163840;  // 256 x 256
  unsigned short* WT40e0 = wb + 229376; // 48 x 128
  unsigned short* WT40e1 = wb + 235520; // 48 x 128
  unsigned short* WT40e2 = wb + 241664; // 48 x 256
  unsigned short* WT40e3 = wb + 253952; // 48 x 256

  dim3 B(256);
  // bucketed CSR build (bcnt block 0 also probes x dtype -> flags[0])
  k_zero<<<dim3(4), B, 0, stream>>>(bcnt, NBKT);
  k_bcnt<<<dim3(391), B, 0, stream>>>(ei, bcnt, (const unsigned*)x_raw, flags);
  k_bscan2<<<dim3(1), dim3(64), 0, stream>>>(bcnt, bbase, gcur);
  k_bstage<<<dim3(391), B, 0, stream>>>(ei, gcur, stage);
  k_bplace<<<dim3(NBKT), B, 0, stream>>>(stage, bbase, offs, dinv, csr_src);

  // convert x (+xs prescale), biases, and raw-W transposes in one dispatch
  CvtP p;
  const int bsrc[7] = {0, 3, 5, 9, 11, 13, 15};
  unsigned short* bdst[7] = {xb, bc0, bc1, be0, be1, be2, be3};
  const int bn[7] = {NNODES * 128, 256, 256, 40, 40, 40, 40};
  for (int i = 0; i < 7; ++i) { p.src[i] = d_in[bsrc[i]]; p.dst[i] = bdst[i]; p.n[i] = bn[i]; }
  const int wsrc[6] = {2, 4, 8, 10, 12, 14};
  unsigned short* wdst[6] = {WTc0, WTc1, WT40e0, WT40e1, WT40e2, WT40e3};
  for (int i = 0; i < 6; ++i) { p.W[i] = d_in[wsrc[i]]; p.WT[i] = wdst[i]; }
  k_cvt<<<dim3(1024, 8), B, 0, stream>>>(p, flags, dinv, xs);

  // layer 0: exit on x
  k_exit0<<<dim3(782), B, 0, stream>>>(xb, WT40e0, be0, out + 0 * 40, dinv);
  // h1 = agg(xs)
  k_agg<128, 16><<<dim3(25000), B, 0, stream>>>(xs, hA, offs, csr_src, dinv);
  // exit1(hA) || hB = relu(hA Wc0 + bc0)*dinv
  k_exit_mlp<128, true><<<dim3(2346), B, 0, stream>>>(hA, WTc0, bc0, hB,
                                                      WT40e1, be1, out + 1 * 40, dinv);
  // h2 = agg(hB)
  k_agg<256, 8><<<dim3(25000), B, 0, stream>>>(hB, hA, offs, csr_src, dinv);
  // exit2(hA) || hB = relu(hA Wc1 + bc1)
  k_exit_mlp<256, false><<<dim3(2346), B, 0, stream>>>(hA, WTc1, bc1, hB,
                                                       WT40e2, be2, out + 2 * 40, dinv);
  // layer 3 push-through: P = (hB @ We3) * dinv
  k_exit3<<<dim3(782), B, 0, stream>>>(hB, WT40e3, P, dinv);
  k_agg40<<<dim3(25000), B, 0, stream>>>(P, offs, csr_src, dinv, be3, out + 3 * 40);
}